// Round 3
// baseline (179.080 us; speedup 1.0000x reference)
//
#include <hip/hip_runtime.h>
#include <math.h>

// Problem constants (from reference)
constexpr int NH    = 778;   // hand verts per batch
constexpr int BLK   = 64;    // 1 wave per block
constexpr int NSLOT = 13;    // 64*13 = 832 >= 778; slot 12 clamped to vertex 777
constexpr int CHUNK = 157;   // obj points per block chunk -> 255 chunks for V=40000

// Kernel 1: per-(batch, obj-chunk) block (one wave) computes running min of
//   d2' = |o|^2 - 2 h.o        (|h|^2 hoisted out of the min)
// over its obj chunk for 13 hand points per lane, using LDS-staged
// (-2ox,-2oy,-2oz,|o|^2) float4s (broadcast ds_read_b128, conflict-free),
// then atomicMin of clamped d2 = max(|h|^2 + min, 0) bit patterns into the
// global [B,NH] buffer (uint ordering valid for non-negative floats).
// Per pair: 3 fma + 1/2 v_min3 = 3.5 VALU ops.
__global__ __launch_bounds__(BLK, 2) void nn_min_kernel(
    const float* __restrict__ hand,   // [B, NH, 3]
    const float* __restrict__ obj,    // [B, V, 3]
    unsigned int* __restrict__ minb,  // [B*NH] min-d2 bits
    int V)
{
    __shared__ float4 s_obj[CHUNK + 3];
    const int b   = blockIdx.y;
    const int c   = blockIdx.x;
    const int tid = threadIdx.x;
    const int j0  = c * CHUNK;
    const int cnt = min(CHUNK, V - j0);   // >= 1 by grid construction

    // stage chunk into LDS as (-2x, -2y, -2z, |o|^2)
    const float* op = obj + ((size_t)b * V + (size_t)j0) * 3;
    for (int i = tid; i < cnt; i += BLK) {
        const float x = op[3 * i + 0];
        const float y = op[3 * i + 1];
        const float z = op[3 * i + 2];
        s_obj[i] = make_float4(-2.f * x, -2.f * y, -2.f * z, x * x + y * y + z * z);
    }
    if (tid < 3) {  // pad to a multiple of 4 with copies of point 0
        const float x = op[0], y = op[1], z = op[2];
        s_obj[cnt + tid] = make_float4(-2.f * x, -2.f * y, -2.f * z, x * x + y * y + z * z);
    }
    __syncthreads();

    // 13 hand points per lane in registers (slot 12 clamped for lanes >= 10)
    const float* hb = hand + (size_t)b * NH * 3;
    float hx[NSLOT], hy[NSLOT], hz[NSLOT], hq[NSLOT], m[NSLOT];
#pragma unroll
    for (int s = 0; s < NSLOT; ++s) {
        const int h = min(tid + s * BLK, NH - 1);
        const float x = hb[h * 3 + 0];
        const float y = hb[h * 3 + 1];
        const float z = hb[h * 3 + 2];
        hx[s] = x; hy[s] = y; hz[s] = z;
        hq[s] = x * x + y * y + z * z;
        m[s]  = 3.4e38f;
    }

    const int cnt4 = (cnt + 3) & ~3;
    for (int j = 0; j < cnt4; j += 4) {
        const float4 o0 = s_obj[j + 0];   // broadcast b128, conflict-free
        const float4 o1 = s_obj[j + 1];
        const float4 o2 = s_obj[j + 2];
        const float4 o3 = s_obj[j + 3];
#pragma unroll
        for (int s = 0; s < NSLOT; ++s) {
            float t0 = fmaf(hx[s], o0.x, o0.w);
            t0 = fmaf(hy[s], o0.y, t0);
            t0 = fmaf(hz[s], o0.z, t0);
            float t1 = fmaf(hx[s], o1.x, o1.w);
            t1 = fmaf(hy[s], o1.y, t1);
            t1 = fmaf(hz[s], o1.z, t1);
            float t2 = fmaf(hx[s], o2.x, o2.w);
            t2 = fmaf(hy[s], o2.y, t2);
            t2 = fmaf(hz[s], o2.z, t2);
            float t3 = fmaf(hx[s], o3.x, o3.w);
            t3 = fmaf(hy[s], o3.y, t3);
            t3 = fmaf(hz[s], o3.z, t3);
            const float a = fminf(fminf(t0, t1), t2);   // v_min3
            m[s] = fminf(fminf(a, t3), m[s]);           // v_min3
        }
    }

#pragma unroll
    for (int s = 0; s < NSLOT; ++s) {
        const int h = tid + s * BLK;
        if (h < NH) {  // skips only the clamped duplicate lanes of slot 12
            const unsigned bits = __float_as_uint(fmaxf(hq[s] + m[s], 0.f));
            unsigned int* p = &minb[b * NH + h];
            // pre-check: a stale read is always >= current global min, so
            // skipping when bits >= *p is safe and cuts hot-line atomics
            if (bits < *((volatile unsigned int*)p)) atomicMin(p, bits);
        }
    }
}

// Kernel 2: single-block final reduction -> 6 scalar outputs
__global__ __launch_bounds__(256) void finalize_kernel(
    const unsigned int* __restrict__ minb,  // [B, NH] bits of min d2
    float* __restrict__ out, int B)
{
    constexpr float COLL = 0.005f;
    constexpr float CONT = 0.01f;
    const int total = B * NH;
    const int tid = threadIdx.x;

    double sum_d = 0.0, pen_sum = 0.0, att_sum = 0.0;
    int pen_cnt = 0, att_cnt = 0;

    for (int i = tid; i < total; i += 256) {
        const float d2 = __uint_as_float(minb[i]);
        const float d  = sqrtf(d2);
        sum_d += (double)d;
        if (d < COLL) {
            const float t = COLL - d;
            pen_sum += (double)(t * t);
            pen_cnt++;
        }
        const int n = i % NH;
        const bool isc = (n == 745) | (n == 317) | (n == 444) | (n == 556) |
                         (n == 673) | (n == 95)  | (n == 182) | (n == 234) |
                         (n == 279) | (n == 320);
        if (isc & (d > COLL) & (d < CONT)) {
            att_sum += (double)(d * d);
            att_cnt++;
        }
    }

    __shared__ double sd[256], sp[256], sa[256];
    __shared__ int    cp[256], ca[256];
    sd[tid] = sum_d; sp[tid] = pen_sum; sa[tid] = att_sum;
    cp[tid] = pen_cnt; ca[tid] = att_cnt;
    __syncthreads();
    for (int off = 128; off > 0; off >>= 1) {
        if (tid < off) {
            sd[tid] += sd[tid + off];
            sp[tid] += sp[tid + off];
            sa[tid] += sa[tid + off];
            cp[tid] += cp[tid + off];
            ca[tid] += ca[tid + off];
        }
        __syncthreads();
    }
    if (tid == 0) {
        const double pen_loss = cp[0] > 0 ? sp[0] / (double)cp[0] : 0.0;
        const double att_loss = ca[0] > 0 ? sa[0] / (double)ca[0] : 0.0;
        out[0] = (float)(100.0 * pen_loss + 10.0 * att_loss);  // contact_loss
        out[1] = (float)pen_loss;                              // pen_loss
        out[2] = (float)att_loss;                              // att_loss
        out[3] = (float)(sd[0] / (double)total);               // dist_mean
        out[4] = (float)ca[0];                                 // num_contacts
        out[5] = (float)cp[0];                                 // num_penetrations
    }
}

extern "C" void kernel_launch(void* const* d_in, const int* in_sizes, int n_in,
                              void* d_out, int out_size, void* d_ws, size_t ws_size,
                              hipStream_t stream) {
    const float* hand = (const float*)d_in[0];  // [B, 778, 3] fp32
    const float* obj  = (const float*)d_in[1];  // [B, V, 3]   fp32
    // d_in[2] (hand_faces), d_in[3] (obj_faces): unused by the loss

    const int B = in_sizes[0] / (NH * 3);
    const int V = in_sizes[1] / (B * 3);
    const int nchunks = (V + CHUNK - 1) / CHUNK;

    unsigned int* minb = (unsigned int*)d_ws;  // [B*NH] min-d2 bit patterns

    // init min buffer to 0x7F7F7F7F (~3.39e38 as float; > any real d2)
    hipMemsetAsync(d_ws, 0x7F, (size_t)B * NH * sizeof(unsigned int), stream);

    dim3 grid(nchunks, B);
    nn_min_kernel<<<grid, BLK, 0, stream>>>(hand, obj, minb, V);
    finalize_kernel<<<1, 256, 0, stream>>>(minb, (float*)d_out, B);
}

// Round 4
// 158.666 us; speedup vs baseline: 1.1287x; 1.1287x over previous
//
#include <hip/hip_runtime.h>
#include <math.h>

// Problem constants (from reference)
constexpr int NH    = 778;   // hand verts per batch
constexpr int BLK   = 128;   // 2 waves per block (measured-best block shape, R1)
constexpr int NSLOT = 6;     // 128*6 = 768 hand points + 10-vert tail loop
constexpr int CHUNK = 157;   // obj points per chunk -> 255 chunks for V=40000

// Kernel 1: per-(batch, obj-chunk) block computes running min of
//   d2' = |o|^2 - 2 h.o          (|h|^2 hoisted out of the min)
// using LDS-staged (-2ox,-2oy,-2oz,|o|^2) float4s (broadcast ds_read_b128),
// then atomicMin of d2 = max(|h|^2 + min, 0) bit patterns (uint ordering is
// valid for non-negative floats), gated by a plain-load pre-check.
//
// Register budget is the whole game (R2/R3 post-mortem: compiler heuristic
// capped VGPRs at 28/40 and spilled the hand arrays into the hot loop).
// Live set here: hx/hy/hz/m x6 = 24 + two float4 = 8 + addressing ~6 -> ~38.
// __launch_bounds__(BLK, 1) lifts the allocator cap (1 wave/EU floor).
__global__ __launch_bounds__(BLK, 1) void nn_min_kernel(
    const float* __restrict__ hand,   // [B, NH, 3]
    const float* __restrict__ obj,    // [B, V, 3]
    unsigned int* __restrict__ minb,  // [B*NH] min-d2 bits
    int V)
{
    __shared__ float4 s_obj[CHUNK + 1];
    const int b   = blockIdx.y;
    const int c   = blockIdx.x;
    const int tid = threadIdx.x;
    const int j0  = c * CHUNK;
    const int cnt = min(CHUNK, V - j0);   // >= 1 by grid construction

    // stage chunk into LDS as (-2x, -2y, -2z, |o|^2)
    const float* op = obj + ((size_t)b * V + (size_t)j0) * 3;
    for (int i = tid; i < cnt; i += BLK) {
        const float x = op[3 * i + 0];
        const float y = op[3 * i + 1];
        const float z = op[3 * i + 2];
        s_obj[i] = make_float4(-2.f * x, -2.f * y, -2.f * z, x * x + y * y + z * z);
    }
    if (tid == 0) {  // pad so the j-loop can run in pairs (duplicate point 0)
        const float x = op[0], y = op[1], z = op[2];
        s_obj[cnt] = make_float4(-2.f * x, -2.f * y, -2.f * z, x * x + y * y + z * z);
    }
    __syncthreads();

    // 6 hand points per lane in registers (no hq in the loop — epilogue only)
    const float* hb = hand + (size_t)b * NH * 3;
    float hx[NSLOT], hy[NSLOT], hz[NSLOT], m[NSLOT];
#pragma unroll
    for (int s = 0; s < NSLOT; ++s) {
        const int h = tid + s * BLK;   // < 768 always
        hx[s] = hb[h * 3 + 0];
        hy[s] = hb[h * 3 + 1];
        hz[s] = hb[h * 3 + 2];
        m[s]  = 3.4e38f;
    }

    const int cnt2 = (cnt + 1) & ~1;
    for (int j = 0; j < cnt2; j += 2) {
        const float4 o0 = s_obj[j];       // broadcast b128, conflict-free
        const float4 o1 = s_obj[j + 1];
#pragma unroll
        for (int s = 0; s < NSLOT; ++s) {
            float t0 = fmaf(hx[s], o0.x, o0.w);
            t0 = fmaf(hy[s], o0.y, t0);
            t0 = fmaf(hz[s], o0.z, t0);
            float t1 = fmaf(hx[s], o1.x, o1.w);
            t1 = fmaf(hy[s], o1.y, t1);
            t1 = fmaf(hz[s], o1.z, t1);
            m[s] = fminf(fminf(t0, t1), m[s]);   // v_min3
        }
    }

#pragma unroll
    for (int s = 0; s < NSLOT; ++s) {
        const int h = tid + s * BLK;
        const float hq = fmaf(hx[s], hx[s], fmaf(hy[s], hy[s], hz[s] * hz[s]));
        const unsigned bits = __float_as_uint(fmaxf(hq + m[s], 0.f));
        unsigned int* p = &minb[b * NH + h];
        // pre-check: a stale read is always >= the true current min, so
        // skipping when bits >= *p is safe; cuts hot-line atomic traffic
        if (bits < *((volatile unsigned int*)p)) atomicMin(p, bits);
    }

    // tail: hand points 768..777 on lanes 0..9 of wave 0 (runs under the
    // other waves' compute; 10/64 lanes active)
    if (tid < NH - NSLOT * BLK) {
        const int h = NSLOT * BLK + tid;
        const float tx = hb[h * 3 + 0];
        const float ty = hb[h * 3 + 1];
        const float tz = hb[h * 3 + 2];
        float tm = 3.4e38f;
        for (int j = 0; j < cnt; ++j) {
            const float4 o = s_obj[j];
            float t = fmaf(tx, o.x, o.w);
            t = fmaf(ty, o.y, t);
            t = fmaf(tz, o.z, t);
            tm = fminf(tm, t);
        }
        const float tq = fmaf(tx, tx, fmaf(ty, ty, tz * tz));
        const unsigned bits = __float_as_uint(fmaxf(tq + tm, 0.f));
        unsigned int* p = &minb[b * NH + h];
        if (bits < *((volatile unsigned int*)p)) atomicMin(p, bits);
    }
}

// Kernel 2: single-block final reduction -> 6 scalar outputs
__global__ __launch_bounds__(256) void finalize_kernel(
    const unsigned int* __restrict__ minb,  // [B, NH] bits of min d2
    float* __restrict__ out, int B)
{
    constexpr float COLL = 0.005f;
    constexpr float CONT = 0.01f;
    const int total = B * NH;
    const int tid = threadIdx.x;

    double sum_d = 0.0, pen_sum = 0.0, att_sum = 0.0;
    int pen_cnt = 0, att_cnt = 0;

    for (int i = tid; i < total; i += 256) {
        const float d2 = __uint_as_float(minb[i]);
        const float d  = sqrtf(d2);
        sum_d += (double)d;
        if (d < COLL) {
            const float t = COLL - d;
            pen_sum += (double)(t * t);
            pen_cnt++;
        }
        const int n = i % NH;
        const bool isc = (n == 745) | (n == 317) | (n == 444) | (n == 556) |
                         (n == 673) | (n == 95)  | (n == 182) | (n == 234) |
                         (n == 279) | (n == 320);
        if (isc & (d > COLL) & (d < CONT)) {
            att_sum += (double)(d * d);
            att_cnt++;
        }
    }

    __shared__ double sd[256], sp[256], sa[256];
    __shared__ int    cp[256], ca[256];
    sd[tid] = sum_d; sp[tid] = pen_sum; sa[tid] = att_sum;
    cp[tid] = pen_cnt; ca[tid] = att_cnt;
    __syncthreads();
    for (int off = 128; off > 0; off >>= 1) {
        if (tid < off) {
            sd[tid] += sd[tid + off];
            sp[tid] += sp[tid + off];
            sa[tid] += sa[tid + off];
            cp[tid] += cp[tid + off];
            ca[tid] += ca[tid + off];
        }
        __syncthreads();
    }
    if (tid == 0) {
        const double pen_loss = cp[0] > 0 ? sp[0] / (double)cp[0] : 0.0;
        const double att_loss = ca[0] > 0 ? sa[0] / (double)ca[0] : 0.0;
        out[0] = (float)(100.0 * pen_loss + 10.0 * att_loss);  // contact_loss
        out[1] = (float)pen_loss;                              // pen_loss
        out[2] = (float)att_loss;                              // att_loss
        out[3] = (float)(sd[0] / (double)total);               // dist_mean
        out[4] = (float)ca[0];                                 // num_contacts
        out[5] = (float)cp[0];                                 // num_penetrations
    }
}

extern "C" void kernel_launch(void* const* d_in, const int* in_sizes, int n_in,
                              void* d_out, int out_size, void* d_ws, size_t ws_size,
                              hipStream_t stream) {
    const float* hand = (const float*)d_in[0];  // [B, 778, 3] fp32
    const float* obj  = (const float*)d_in[1];  // [B, V, 3]   fp32
    // d_in[2] (hand_faces), d_in[3] (obj_faces): unused by the loss

    const int B = in_sizes[0] / (NH * 3);
    const int V = in_sizes[1] / (B * 3);
    const int nchunks = (V + CHUNK - 1) / CHUNK;

    unsigned int* minb = (unsigned int*)d_ws;  // [B*NH] min-d2 bit patterns

    // init min buffer to 0x7F7F7F7F (~3.39e38 as float; > any real d2)
    hipMemsetAsync(d_ws, 0x7F, (size_t)B * NH * sizeof(unsigned int), stream);

    dim3 grid(nchunks, B);
    nn_min_kernel<<<grid, BLK, 0, stream>>>(hand, obj, minb, V);
    finalize_kernel<<<1, 256, 0, stream>>>(minb, (float*)d_out, B);
}

// Round 5
// 148.330 us; speedup vs baseline: 1.2073x; 1.0697x over previous
//
#include <hip/hip_runtime.h>
#include <math.h>

// Problem constants (from reference)
constexpr int NH    = 778;   // hand verts per batch
constexpr int BLK   = 256;   // 4 waves per block
constexpr int NSLOT = 3;     // 256*3 = 768 hand points + 10-vert tail loop
constexpr int CHUNK = 157;   // obj points per chunk -> 255 chunks for V=40000

// ---------------------------------------------------------------------------
// Prepass: tf[b][i] = (-2x, -2y, -2z, |o|^2) float4 (sentinel past V so the
// main loop can over-read groups of 4 without masking). Also initializes the
// [B*NH] min buffer to 0x7F7F7F7F (~3.39e38f), replacing the memset dispatch.
// ---------------------------------------------------------------------------
__global__ __launch_bounds__(256) void transform_kernel(
    const float* __restrict__ obj,   // [B, V, 3]
    float4* __restrict__ tf,         // [B, Vpad]
    unsigned int* __restrict__ minb, // [B*NH]
    int V, int Vpad, int B)
{
    const int i = blockIdx.x * 256 + threadIdx.x;
    if (i < B * NH) minb[i] = 0x7F7F7F7Fu;
    const int total = B * Vpad;
    if (i >= total) return;
    const int b = i / Vpad;
    const int j = i - b * Vpad;
    if (j < V) {
        const float* p = obj + ((size_t)b * V + j) * 3;
        const float x = p[0], y = p[1], z = p[2];
        tf[i] = make_float4(-2.f * x, -2.f * y, -2.f * z,
                            fmaf(x, x, fmaf(y, y, z * z)));
    } else {
        tf[i] = make_float4(0.f, 0.f, 0.f, 3.4e38f);  // never the min
    }
}

// ---------------------------------------------------------------------------
// Main NN kernel (primary path): obj points are wave-uniform -> read them
// through the SCALAR pipe (uniform address => s_load_dwordx4/x16 into SGPRs)
// and consume as scalar operands of v_fma. No LDS, no per-iteration vector
// memory, no __syncthreads. R1-R4 post-mortem: the inner-loop broadcast
// ds_read latency (~120cyc, ~1-deep pipelining) capped VALUBusy at ~31-35%
// in every variant; this removes that dependence entirely.
//   d2' = |o|^2 - 2 h.o  (|h|^2 added in the epilogue)
// Over-reading past the chunk (group-of-4 rounding) touches valid same-batch
// points or sentinels -> global atomicMin result unchanged.
// ---------------------------------------------------------------------------
__global__ __launch_bounds__(BLK) void nn_min_kernel(
    const float* __restrict__ hand,    // [B, NH, 3]
    const float4* __restrict__ tf,     // [B, Vpad] transformed
    unsigned int* __restrict__ minb,   // [B*NH] min-d2 bits
    int V, int Vpad)
{
    const int b   = blockIdx.y;
    const int c   = blockIdx.x;
    const int tid = threadIdx.x;
    const int j0  = c * CHUNK;
    const int cnt = min(CHUNK, V - j0);     // >= 1 by grid construction
    const int ng  = (cnt + 3) >> 2;         // groups of 4 (may over-read: OK)

    const float4* tp = tf + (size_t)b * Vpad + j0;   // uniform pointer

    // 3 hand points per lane in registers
    const float* hb = hand + (size_t)b * NH * 3;
    float hx[NSLOT], hy[NSLOT], hz[NSLOT], m[NSLOT];
#pragma unroll
    for (int s = 0; s < NSLOT; ++s) {
        const int h = tid + s * BLK;   // < 768 always
        hx[s] = hb[h * 3 + 0];
        hy[s] = hb[h * 3 + 1];
        hz[s] = hb[h * 3 + 2];
        m[s]  = 3.4e38f;
    }

#pragma unroll 2
    for (int g = 0; g < ng; ++g) {
        // uniform loads -> SGPRs via SMEM pipe (separate from VALU/LDS)
        const float4 o0 = tp[4 * g + 0];
        const float4 o1 = tp[4 * g + 1];
        const float4 o2 = tp[4 * g + 2];
        const float4 o3 = tp[4 * g + 3];
#pragma unroll
        for (int s = 0; s < NSLOT; ++s) {
            float t0 = fmaf(hz[s], o0.z, o0.w);
            t0 = fmaf(hy[s], o0.y, t0);
            t0 = fmaf(hx[s], o0.x, t0);
            float t1 = fmaf(hz[s], o1.z, o1.w);
            t1 = fmaf(hy[s], o1.y, t1);
            t1 = fmaf(hx[s], o1.x, t1);
            float t2 = fmaf(hz[s], o2.z, o2.w);
            t2 = fmaf(hy[s], o2.y, t2);
            t2 = fmaf(hx[s], o2.x, t2);
            float t3 = fmaf(hz[s], o3.z, o3.w);
            t3 = fmaf(hy[s], o3.y, t3);
            t3 = fmaf(hx[s], o3.x, t3);
            m[s] = fminf(fminf(fminf(t0, t1), t2), fminf(t3, m[s]));
        }
    }

#pragma unroll
    for (int s = 0; s < NSLOT; ++s) {
        const int h = tid + s * BLK;
        const float hq = fmaf(hx[s], hx[s], fmaf(hy[s], hy[s], hz[s] * hz[s]));
        const unsigned bits = __float_as_uint(fmaxf(hq + m[s], 0.f));
        unsigned int* p = &minb[b * NH + h];
        // stale read >= true min, so skipping when bits >= *p is safe
        if (bits < *((volatile unsigned int*)p)) atomicMin(p, bits);
    }

    // tail: hand points 768..777 on lanes 0..9 of wave 0
    if (tid < NH - NSLOT * BLK) {
        const int h = NSLOT * BLK + tid;
        const float tx = hb[h * 3 + 0];
        const float ty = hb[h * 3 + 1];
        const float tz = hb[h * 3 + 2];
        float tm = 3.4e38f;
        for (int g = 0; g < ng; ++g) {
            const float4 o0 = tp[4 * g + 0];
            const float4 o1 = tp[4 * g + 1];
            const float4 o2 = tp[4 * g + 2];
            const float4 o3 = tp[4 * g + 3];
            float t0 = fmaf(tz, o0.z, o0.w); t0 = fmaf(ty, o0.y, t0); t0 = fmaf(tx, o0.x, t0);
            float t1 = fmaf(tz, o1.z, o1.w); t1 = fmaf(ty, o1.y, t1); t1 = fmaf(tx, o1.x, t1);
            float t2 = fmaf(tz, o2.z, o2.w); t2 = fmaf(ty, o2.y, t2); t2 = fmaf(tx, o2.x, t2);
            float t3 = fmaf(tz, o3.z, o3.w); t3 = fmaf(ty, o3.y, t3); t3 = fmaf(tx, o3.x, t3);
            tm = fminf(fminf(fminf(t0, t1), t2), fminf(t3, tm));
        }
        const float tq = fmaf(tx, tx, fmaf(ty, ty, tz * tz));
        const unsigned bits = __float_as_uint(fmaxf(tq + tm, 0.f));
        unsigned int* p = &minb[b * NH + h];
        if (bits < *((volatile unsigned int*)p)) atomicMin(p, bits);
    }
}

// ---------------------------------------------------------------------------
// Fallback (if ws too small for tf): raw obj via uniform scalar loads,
// subtract form (s_ox - hx)^2 ... ; src0 may be SGPR so 1-SGPR rule holds.
// ---------------------------------------------------------------------------
__global__ __launch_bounds__(BLK) void nn_min_raw_kernel(
    const float* __restrict__ hand, const float* __restrict__ obj,
    unsigned int* __restrict__ minb, int V)
{
    const int b   = blockIdx.y;
    const int c   = blockIdx.x;
    const int tid = threadIdx.x;
    const int j0  = c * CHUNK;
    const int cnt = min(CHUNK, V - j0);
    const float* op = obj + ((size_t)b * V + j0) * 3;  // uniform

    const float* hb = hand + (size_t)b * NH * 3;
    float hx[NSLOT], hy[NSLOT], hz[NSLOT], m[NSLOT];
#pragma unroll
    for (int s = 0; s < NSLOT; ++s) {
        const int h = tid + s * BLK;
        hx[s] = hb[h * 3 + 0];
        hy[s] = hb[h * 3 + 1];
        hz[s] = hb[h * 3 + 2];
        m[s]  = 3.4e38f;
    }
#pragma unroll 2
    for (int j = 0; j < cnt; ++j) {
        const float ox = op[3 * j + 0], oy = op[3 * j + 1], oz = op[3 * j + 2];
#pragma unroll
        for (int s = 0; s < NSLOT; ++s) {
            const float dx = ox - hx[s], dy = oy - hy[s], dz = oz - hz[s];
            m[s] = fminf(m[s], fmaf(dx, dx, fmaf(dy, dy, dz * dz)));
        }
    }
#pragma unroll
    for (int s = 0; s < NSLOT; ++s) {
        const int h = tid + s * BLK;
        const unsigned bits = __float_as_uint(fmaxf(m[s], 0.f));
        unsigned int* p = &minb[b * NH + h];
        if (bits < *((volatile unsigned int*)p)) atomicMin(p, bits);
    }
    if (tid < NH - NSLOT * BLK) {
        const int h = NSLOT * BLK + tid;
        const float tx = hb[h * 3 + 0], ty = hb[h * 3 + 1], tz = hb[h * 3 + 2];
        float tm = 3.4e38f;
        for (int j = 0; j < cnt; ++j) {
            const float dx = op[3 * j + 0] - tx;
            const float dy = op[3 * j + 1] - ty;
            const float dz = op[3 * j + 2] - tz;
            tm = fminf(tm, fmaf(dx, dx, fmaf(dy, dy, dz * dz)));
        }
        unsigned int* p = &minb[b * NH + h];
        const unsigned bits = __float_as_uint(fmaxf(tm, 0.f));
        if (bits < *((volatile unsigned int*)p)) atomicMin(p, bits);
    }
}

// Kernel 3: single-block final reduction -> 6 scalar outputs
__global__ __launch_bounds__(256) void finalize_kernel(
    const unsigned int* __restrict__ minb, float* __restrict__ out, int B)
{
    constexpr float COLL = 0.005f;
    constexpr float CONT = 0.01f;
    const int total = B * NH;
    const int tid = threadIdx.x;

    double sum_d = 0.0, pen_sum = 0.0, att_sum = 0.0;
    int pen_cnt = 0, att_cnt = 0;
    for (int i = tid; i < total; i += 256) {
        const float d2 = __uint_as_float(minb[i]);
        const float d  = sqrtf(d2);
        sum_d += (double)d;
        if (d < COLL) { const float t = COLL - d; pen_sum += (double)(t * t); pen_cnt++; }
        const int n = i % NH;
        const bool isc = (n == 745) | (n == 317) | (n == 444) | (n == 556) |
                         (n == 673) | (n == 95)  | (n == 182) | (n == 234) |
                         (n == 279) | (n == 320);
        if (isc & (d > COLL) & (d < CONT)) { att_sum += (double)(d * d); att_cnt++; }
    }

    __shared__ double sd[256], sp[256], sa[256];
    __shared__ int    cp[256], ca[256];
    sd[tid] = sum_d; sp[tid] = pen_sum; sa[tid] = att_sum;
    cp[tid] = pen_cnt; ca[tid] = att_cnt;
    __syncthreads();
    for (int off = 128; off > 0; off >>= 1) {
        if (tid < off) {
            sd[tid] += sd[tid + off]; sp[tid] += sp[tid + off];
            sa[tid] += sa[tid + off];
            cp[tid] += cp[tid + off]; ca[tid] += ca[tid + off];
        }
        __syncthreads();
    }
    if (tid == 0) {
        const double pen_loss = cp[0] > 0 ? sp[0] / (double)cp[0] : 0.0;
        const double att_loss = ca[0] > 0 ? sa[0] / (double)ca[0] : 0.0;
        out[0] = (float)(100.0 * pen_loss + 10.0 * att_loss);
        out[1] = (float)pen_loss;
        out[2] = (float)att_loss;
        out[3] = (float)(sd[0] / (double)total);
        out[4] = (float)ca[0];
        out[5] = (float)cp[0];
    }
}

extern "C" void kernel_launch(void* const* d_in, const int* in_sizes, int n_in,
                              void* d_out, int out_size, void* d_ws, size_t ws_size,
                              hipStream_t stream) {
    const float* hand = (const float*)d_in[0];  // [B, 778, 3] fp32
    const float* obj  = (const float*)d_in[1];  // [B, V, 3]   fp32
    // d_in[2] (hand_faces), d_in[3] (obj_faces): unused by the loss

    const int B = in_sizes[0] / (NH * 3);
    const int V = in_sizes[1] / (B * 3);
    const int nchunks = (V + CHUNK - 1) / CHUNK;
    const int Vpad = ((nchunks * CHUNK + 3) & ~3) + 4;  // group-of-4 over-read safe

    unsigned int* minb = (unsigned int*)d_ws;           // [B*NH] min-d2 bits
    float4* tf = (float4*)((char*)d_ws + 65536);        // [B*Vpad] transformed
    const size_t need = 65536 + (size_t)B * Vpad * sizeof(float4);

    dim3 grid(nchunks, B);
    if (ws_size >= need) {
        const int tot = B * Vpad;
        transform_kernel<<<(tot + 255) / 256, 256, 0, stream>>>(obj, tf, minb, V, Vpad, B);
        nn_min_kernel<<<grid, BLK, 0, stream>>>(hand, tf, minb, V, Vpad);
    } else {
        hipMemsetAsync(d_ws, 0x7F, (size_t)B * NH * sizeof(unsigned int), stream);
        nn_min_raw_kernel<<<grid, BLK, 0, stream>>>(hand, obj, minb, V);
    }
    finalize_kernel<<<1, 256, 0, stream>>>(minb, (float*)d_out, B);
}

// Round 6
// 109.325 us; speedup vs baseline: 1.6380x; 1.3568x over previous
//
#include <hip/hip_runtime.h>
#include <math.h>

// Problem constants
constexpr int NH     = 778;    // hand verts per batch
constexpr int T      = 16;     // hand points per block (SGPR-resident tile)
constexpr int NTILES = (NH + T - 1) / T;    // 49 (784 padded hand points)
constexpr int NHPAD  = NTILES * T;          // 784
constexpr int BLK    = 256;    // 4 waves
constexpr int CHUNKP = 2560;   // obj points per block chunk
constexpr int LPP    = CHUNKP / BLK;        // 10 obj points per lane

// ---------------------------------------------------------------------------
// Prepass: obj tf[b][j] = (x,y,z,|o|^2) (sentinel w=3.4e38 past V),
//          hand tf[b][i] = (-2hx,-2hy,-2hz,|h|^2) (pad i>=NH clamped),
//          minb init to 0x7F7F7F7F.
// ---------------------------------------------------------------------------
__global__ __launch_bounds__(256) void transform_kernel(
    const float* __restrict__ hand,  // [B, NH, 3]
    const float* __restrict__ obj,   // [B, V, 3]
    float4* __restrict__ otf,        // [B, Vpad]
    float4* __restrict__ htf,        // [B, NHPAD]
    unsigned int* __restrict__ minb, // [B*NH]
    int V, int Vpad, int B)
{
    const int i = blockIdx.x * 256 + threadIdx.x;
    if (i < B * NH) minb[i] = 0x7F7F7F7Fu;
    if (i < B * NHPAD) {
        const int b = i / NHPAD;
        const int h = min(i - b * NHPAD, NH - 1);
        const float* p = hand + ((size_t)b * NH + h) * 3;
        const float x = p[0], y = p[1], z = p[2];
        htf[i] = make_float4(-2.f * x, -2.f * y, -2.f * z,
                             fmaf(x, x, fmaf(y, y, z * z)));
    }
    if (i < B * Vpad) {
        const int b = i / Vpad;
        const int j = i - b * Vpad;
        if (j < V) {
            const float* p = obj + ((size_t)b * V + j) * 3;
            const float x = p[0], y = p[1], z = p[2];
            otf[i] = make_float4(x, y, z, fmaf(x, x, fmaf(y, y, z * z)));
        } else {
            otf[i] = make_float4(0.f, 0.f, 0.f, 3.4e38f);  // never the min
        }
    }
}

// ---------------------------------------------------------------------------
// Main NN kernel. R1-R5 post-mortem: any wave-uniform inner-loop load (LDS
// broadcast or SMEM scalar) stalls on a drain-wait and caps VALUBusy at
// ~30-55%. So: hand tile (16 pts) lives in SGPRs, loaded ONCE per block;
// obj points stream per-lane through VGPRs via coalesced global_load_dwordx4
// (vmcnt fine-grained waits -> deep pipelining). Per obj point x hand point:
//   t = fma(-2hx, ox, oq); t = fma(-2hy, oy, t); t = fma(-2hz, oz, t);
//   m = min(m, t)            // d2' = |o|^2 - 2 h.o ; |h|^2 added in epilogue
// Each v_fma has exactly one SGPR operand. No barriers in the main loop.
// Epilogue: shfl-xor wave min-reduce, LDS cross-wave reduce, pre-checked
// atomicMin per hand point (uint order valid for non-negative floats).
// ---------------------------------------------------------------------------
__global__ __launch_bounds__(BLK, 4) void nn_min_kernel(
    const float4* __restrict__ otf,  // [B, Vpad] (x,y,z,q)
    const float4* __restrict__ htf,  // [B, NHPAD] (-2x,-2y,-2z,q)
    unsigned int* __restrict__ minb, // [B*NH]
    int Vpad)
{
    const int tile = blockIdx.x;   // hand tile   (fastest -> chunk sharing)
    const int c    = blockIdx.y;   // obj chunk
    const int b    = blockIdx.z;   // batch
    const int tid  = threadIdx.x;

    // hand tile -> scalar registers (uniform address => s_load, once)
    const float4* hp = htf + (size_t)b * NHPAD + tile * T;
    float4 h[T];
#pragma unroll
    for (int t = 0; t < T; ++t) h[t] = hp[t];

    // per-lane obj stream
    const float4* op = otf + (size_t)b * Vpad + c * CHUNKP + tid;
    float m[T];
#pragma unroll
    for (int t = 0; t < T; ++t) m[t] = 3.4e38f;

#pragma unroll
    for (int k = 0; k < LPP; ++k) {
        const float4 o = op[k * BLK];   // coalesced dwordx4, deep vmcnt pipe
#pragma unroll
        for (int t = 0; t < T; ++t) {
            float v = fmaf(h[t].x, o.x, o.w);
            v = fmaf(h[t].y, o.y, v);
            v = fmaf(h[t].z, o.z, v);
            m[t] = fminf(m[t], v);
        }
    }

    // add |h|^2 (uniform per t) and reduce across the wave
#pragma unroll
    for (int t = 0; t < T; ++t) {
        float v = m[t] + h[t].w;
#pragma unroll
        for (int d = 1; d < 64; d <<= 1)
            v = fminf(v, __shfl_xor(v, d));
        m[t] = v;   // all lanes now hold the wave min
    }

    __shared__ float red[4][T];
    const int wave = tid >> 6;
    const int lane = tid & 63;
    if (lane == 0) {
#pragma unroll
        for (int t = 0; t < T; ++t) red[wave][t] = m[t];
    }
    __syncthreads();

    if (tid < T) {
        const float v = fminf(fminf(red[0][tid], red[1][tid]),
                              fminf(red[2][tid], red[3][tid]));
        const int hidx = tile * T + tid;
        if (hidx < NH) {
            const unsigned bits = __float_as_uint(fmaxf(v, 0.f));
            unsigned int* p = &minb[b * NH + hidx];
            // stale read >= true min, so skipping when bits >= *p is safe
            if (bits < *((volatile unsigned int*)p)) atomicMin(p, bits);
        }
    }
}

// ---------------------------------------------------------------------------
// Fallback (ws too small for tf buffers): R5's scalar-pipe kernel on raw obj.
// ---------------------------------------------------------------------------
constexpr int FBLK = 256, FSLOT = 3, FCHUNK = 157;
__global__ __launch_bounds__(FBLK) void nn_min_raw_kernel(
    const float* __restrict__ hand, const float* __restrict__ obj,
    unsigned int* __restrict__ minb, int V)
{
    const int b = blockIdx.y, c = blockIdx.x, tid = threadIdx.x;
    const int j0 = c * FCHUNK;
    const int cnt = min(FCHUNK, V - j0);
    const float* op = obj + ((size_t)b * V + j0) * 3;
    const float* hb = hand + (size_t)b * NH * 3;
    float hx[FSLOT], hy[FSLOT], hz[FSLOT], m[FSLOT];
#pragma unroll
    for (int s = 0; s < FSLOT; ++s) {
        const int h = tid + s * FBLK;
        hx[s] = hb[h * 3 + 0]; hy[s] = hb[h * 3 + 1]; hz[s] = hb[h * 3 + 2];
        m[s] = 3.4e38f;
    }
#pragma unroll 2
    for (int j = 0; j < cnt; ++j) {
        const float ox = op[3 * j + 0], oy = op[3 * j + 1], oz = op[3 * j + 2];
#pragma unroll
        for (int s = 0; s < FSLOT; ++s) {
            const float dx = ox - hx[s], dy = oy - hy[s], dz = oz - hz[s];
            m[s] = fminf(m[s], fmaf(dx, dx, fmaf(dy, dy, dz * dz)));
        }
    }
#pragma unroll
    for (int s = 0; s < FSLOT; ++s) {
        const int h = tid + s * FBLK;
        const unsigned bits = __float_as_uint(fmaxf(m[s], 0.f));
        unsigned int* p = &minb[b * NH + h];
        if (bits < *((volatile unsigned int*)p)) atomicMin(p, bits);
    }
    if (tid < NH - FSLOT * FBLK) {
        const int h = FSLOT * FBLK + tid;
        const float tx = hb[h * 3 + 0], ty = hb[h * 3 + 1], tz = hb[h * 3 + 2];
        float tm = 3.4e38f;
        for (int j = 0; j < cnt; ++j) {
            const float dx = op[3 * j + 0] - tx;
            const float dy = op[3 * j + 1] - ty;
            const float dz = op[3 * j + 2] - tz;
            tm = fminf(tm, fmaf(dx, dx, fmaf(dy, dy, dz * dz)));
        }
        unsigned int* p = &minb[b * NH + h];
        const unsigned bits = __float_as_uint(fmaxf(tm, 0.f));
        if (bits < *((volatile unsigned int*)p)) atomicMin(p, bits);
    }
}

// Final reduction -> 6 scalar outputs
__global__ __launch_bounds__(256) void finalize_kernel(
    const unsigned int* __restrict__ minb, float* __restrict__ out, int B)
{
    constexpr float COLL = 0.005f;
    constexpr float CONT = 0.01f;
    const int total = B * NH;
    const int tid = threadIdx.x;

    double sum_d = 0.0, pen_sum = 0.0, att_sum = 0.0;
    int pen_cnt = 0, att_cnt = 0;
    for (int i = tid; i < total; i += 256) {
        const float d = sqrtf(__uint_as_float(minb[i]));
        sum_d += (double)d;
        if (d < COLL) { const float t = COLL - d; pen_sum += (double)(t * t); pen_cnt++; }
        const int n = i % NH;
        const bool isc = (n == 745) | (n == 317) | (n == 444) | (n == 556) |
                         (n == 673) | (n == 95)  | (n == 182) | (n == 234) |
                         (n == 279) | (n == 320);
        if (isc & (d > COLL) & (d < CONT)) { att_sum += (double)(d * d); att_cnt++; }
    }

    __shared__ double sd[256], sp[256], sa[256];
    __shared__ int    cp[256], ca[256];
    sd[tid] = sum_d; sp[tid] = pen_sum; sa[tid] = att_sum;
    cp[tid] = pen_cnt; ca[tid] = att_cnt;
    __syncthreads();
    for (int off = 128; off > 0; off >>= 1) {
        if (tid < off) {
            sd[tid] += sd[tid + off]; sp[tid] += sp[tid + off];
            sa[tid] += sa[tid + off];
            cp[tid] += cp[tid + off]; ca[tid] += ca[tid + off];
        }
        __syncthreads();
    }
    if (tid == 0) {
        const double pen_loss = cp[0] > 0 ? sp[0] / (double)cp[0] : 0.0;
        const double att_loss = ca[0] > 0 ? sa[0] / (double)ca[0] : 0.0;
        out[0] = (float)(100.0 * pen_loss + 10.0 * att_loss);
        out[1] = (float)pen_loss;
        out[2] = (float)att_loss;
        out[3] = (float)(sd[0] / (double)total);
        out[4] = (float)ca[0];
        out[5] = (float)cp[0];
    }
}

extern "C" void kernel_launch(void* const* d_in, const int* in_sizes, int n_in,
                              void* d_out, int out_size, void* d_ws, size_t ws_size,
                              hipStream_t stream) {
    const float* hand = (const float*)d_in[0];  // [B, 778, 3] fp32
    const float* obj  = (const float*)d_in[1];  // [B, V, 3]   fp32
    // d_in[2]/d_in[3] (faces): unused by the loss

    const int B = in_sizes[0] / (NH * 3);
    const int V = in_sizes[1] / (B * 3);
    const int nchunks = (V + CHUNKP - 1) / CHUNKP;
    const int Vpad = nchunks * CHUNKP;

    unsigned int* minb = (unsigned int*)d_ws;                    // [B*NH]
    float4* htf = (float4*)((char*)d_ws + 65536);                // [B*NHPAD]
    float4* otf = (float4*)((char*)d_ws + 65536 + 131072);       // [B*Vpad]
    const size_t need = 65536 + 131072 + (size_t)B * Vpad * sizeof(float4);

    if (ws_size >= need) {
        const int tot = B * Vpad;
        transform_kernel<<<(tot + 255) / 256, 256, 0, stream>>>(
            hand, obj, otf, htf, minb, V, Vpad, B);
        dim3 grid(NTILES, nchunks, B);
        nn_min_kernel<<<grid, BLK, 0, stream>>>(otf, htf, minb, Vpad);
    } else {
        hipMemsetAsync(d_ws, 0x7F, (size_t)B * NH * sizeof(unsigned int), stream);
        dim3 grid((V + FCHUNK - 1) / FCHUNK, B);
        nn_min_raw_kernel<<<grid, FBLK, 0, stream>>>(hand, obj, minb, V);
    }
    finalize_kernel<<<1, 256, 0, stream>>>(minb, (float*)d_out, B);
}